// Round 3
// baseline (71152.350 us; speedup 1.0000x reference)
//
#include <hip/hip_runtime.h>
#include <hip/hip_bf16.h>

#define SEQ   4096
#define IDIM  2048
#define HDIM  2048
#define G4    8192
#define NBLK  256

// ---------------- numerics (v_exp2 / v_rcp based, ~1e-6 rel err) ----------------
__device__ __forceinline__ float fast_sig(float x) {
    float e = __builtin_amdgcn_exp2f(-1.4426950408889634f * x);   // exp(-x)
    return __builtin_amdgcn_rcpf(1.0f + e);
}
__device__ __forceinline__ float fast_tanh(float x) {
    float e = __builtin_amdgcn_exp2f(2.8853900817779268f * x);    // exp(2x)
    return 1.0f - 2.0f * __builtin_amdgcn_rcpf(e + 1.0f);
}

// ---------------- phase 1: xg[s][g] = x[s,:] . Wih[g,:] + bih[g] + bhh[g] (bf16 store) ---
#define BM 128
#define BN 128
#define BK 16
#define LSTR (BM + 4)   // 132 words: rows stay 16B-aligned (528 = 33*16), write conflicts 2-way (free)

__global__ __launch_bounds__(256, 4)
void xg_gemm(const float* __restrict__ x, const float* __restrict__ Wih,
             const float* __restrict__ bih, const float* __restrict__ bhh,
             __hip_bfloat16* __restrict__ xg)
{
    __shared__ float As[BK][LSTR];   // [k][s]
    __shared__ float Bs[BK][LSTR];   // [k][g]
    const int t  = threadIdx.x;
    const int bG = blockIdx.x;            // 64 tiles over G4
    const int bS = blockIdx.y;            // 32 tiles over SEQ
    const int s0 = bS * BM, g0 = bG * BN;
    const int tx = t & 15, ty = t >> 4;   // 16x16 thread grid, 8x8 microtile
    const int lr = t >> 1, lk = (t & 1) * 8;

    float acc[8][8];
#pragma unroll
    for (int r = 0; r < 8; ++r)
#pragma unroll
        for (int c = 0; c < 8; ++c) acc[r][c] = 0.0f;

    const float* xp = x   + (size_t)(s0 + lr) * IDIM + lk;
    const float* wp = Wih + (size_t)(g0 + lr) * IDIM + lk;

    for (int k0 = 0; k0 < IDIM; k0 += BK) {
        float4 a0 = *(const float4*)(xp + k0);
        float4 a1 = *(const float4*)(xp + k0 + 4);
        float4 b0 = *(const float4*)(wp + k0);
        float4 b1 = *(const float4*)(wp + k0 + 4);
        __syncthreads();
        As[lk+0][lr] = a0.x; As[lk+1][lr] = a0.y; As[lk+2][lr] = a0.z; As[lk+3][lr] = a0.w;
        As[lk+4][lr] = a1.x; As[lk+5][lr] = a1.y; As[lk+6][lr] = a1.z; As[lk+7][lr] = a1.w;
        Bs[lk+0][lr] = b0.x; Bs[lk+1][lr] = b0.y; Bs[lk+2][lr] = b0.z; Bs[lk+3][lr] = b0.w;
        Bs[lk+4][lr] = b1.x; Bs[lk+5][lr] = b1.y; Bs[lk+6][lr] = b1.z; Bs[lk+7][lr] = b1.w;
        __syncthreads();
#pragma unroll
        for (int k = 0; k < BK; ++k) {
            float4 ra0 = *(const float4*)&As[k][ty*8];
            float4 ra1 = *(const float4*)&As[k][ty*8+4];
            float4 rb0 = *(const float4*)&Bs[k][tx*8];
            float4 rb1 = *(const float4*)&Bs[k][tx*8+4];
            float ra[8] = {ra0.x,ra0.y,ra0.z,ra0.w,ra1.x,ra1.y,ra1.z,ra1.w};
            float rb[8] = {rb0.x,rb0.y,rb0.z,rb0.w,rb1.x,rb1.y,rb1.z,rb1.w};
#pragma unroll
            for (int r = 0; r < 8; ++r)
#pragma unroll
                for (int c = 0; c < 8; ++c) acc[r][c] += ra[r] * rb[c];
        }
    }

    float bias[8];
#pragma unroll
    for (int c = 0; c < 8; ++c) {
        int g = g0 + tx*8 + c;
        bias[c] = bih[g] + bhh[g];
    }
#pragma unroll
    for (int r = 0; r < 8; ++r) {
        union { __hip_bfloat16 h[8]; uint4 u; } pk;
#pragma unroll
        for (int c = 0; c < 8; ++c) pk.h[c] = __float2bfloat16(acc[r][c] + bias[c]);
        *(uint4*)&xg[(size_t)(s0 + ty*8 + r) * G4 + g0 + tx*8] = pk.u;
    }
}

// ---------------- phase 2: persistent LSTM recurrence --------------------------
// 256 blocks x 256 threads, 1 block/CU. Block b owns h indices [8b, 8b+8).
// Wave w = gate w (i,f,g,o). Lane L: rg=L>>4 (2 rows: m=2rg,2rg+1), cg=L&15
// (col chunks 4*(cg+16j)). W_hh slice lives in 256 VGPRs per thread.
// Per-step device sync: per-block slot flags (no atomic contention), double-
// buffered h in global memory.
__global__ __launch_bounds__(256, 1)
void lstm_rec(const float* __restrict__ Whh,
              const __hip_bfloat16* __restrict__ xg,
              float* __restrict__ hbuf,            // [2][HDIM], zeroed
              unsigned int* __restrict__ slots)    // [NBLK], zeroed
{
    __shared__ float hsh[HDIM];
    __shared__ float gsum[4][8];
    __shared__ float xgl[32];
    __shared__ float csh[8];

    const int t  = threadIdx.x;
    const int b  = blockIdx.x;
    const int w  = t >> 6;
    const int L  = t & 63;
    const int rg = L >> 4;
    const int cg = L & 15;

    float4 wv[2][32];
#pragma unroll
    for (int mp = 0; mp < 2; ++mp) {
        const float* rp = Whh + (size_t)(w * HDIM + 8 * b + 2 * rg + mp) * HDIM + 4 * cg;
#pragma unroll
        for (int j = 0; j < 32; ++j) wv[mp][j] = *(const float4*)(rp + 64 * j);
    }
    if (t < 8) csh[t] = 0.0f;

    for (int s = 0; s < SEQ; ++s) {
        const float* hr = hbuf + (s & 1) * HDIM;
        float*       hw = hbuf + ((s + 1) & 1) * HDIM;

        // stage h_{s} (fresh via acquire fence at end of prev iter; s=0 reads zeros)
        float4 h0 = *(const float4*)(hr + 8 * t);
        float4 h1 = *(const float4*)(hr + 8 * t + 4);
        float xval = 0.0f;
        if (t < 32)
            xval = __bfloat162float(xg[(size_t)s * G4 + (size_t)(t >> 3) * HDIM + 8 * b + (t & 7)]);
        *(float4*)&hsh[8 * t]     = h0;
        *(float4*)&hsh[8 * t + 4] = h1;
        if (t < 32) xgl[t] = xval;
        __syncthreads();                                   // #1

        float a0 = 0.0f, a1 = 0.0f;
#pragma unroll
        for (int j = 0; j < 32; ++j) {
            float4 hv = *(const float4*)&hsh[4 * (cg + 16 * j)];
            a0 += wv[0][j].x * hv.x; a0 += wv[0][j].y * hv.y;
            a0 += wv[0][j].z * hv.z; a0 += wv[0][j].w * hv.w;
            a1 += wv[1][j].x * hv.x; a1 += wv[1][j].y * hv.y;
            a1 += wv[1][j].z * hv.z; a1 += wv[1][j].w * hv.w;
        }
#pragma unroll
        for (int mask = 1; mask <= 8; mask <<= 1) {        // reduce over cg (16 lanes)
            a0 += __shfl_xor(a0, mask, 64);
            a1 += __shfl_xor(a1, mask, 64);
        }
        if (cg == 0) { gsum[w][2 * rg] = a0; gsum[w][2 * rg + 1] = a1; }
        __syncthreads();                                   // #2

        if (t < 8) {
            float pi = gsum[0][t] + xgl[t];
            float pf = gsum[1][t] + xgl[8 + t];
            float pg = gsum[2][t] + xgl[16 + t];
            float po = gsum[3][t] + xgl[24 + t];
            float c  = fast_sig(pf) * csh[t] + fast_sig(pi) * fast_tanh(pg);
            csh[t] = c;
            float h  = fast_sig(po) * fast_tanh(c);
            __hip_atomic_store(&hw[8 * b + t], h, __ATOMIC_RELAXED, __HIP_MEMORY_SCOPE_AGENT);
        }
        __syncthreads();                                   // #3 (h stores happen-before release)

        if (t == 0)
            __hip_atomic_store(&slots[b], (unsigned int)(s + 1),
                               __ATOMIC_RELEASE, __HIP_MEMORY_SCOPE_AGENT);
        if (s + 1 < SEQ) {
            const unsigned int tgt = (unsigned int)(s + 1);
            while (__hip_atomic_load(&slots[t], __ATOMIC_RELAXED,
                                     __HIP_MEMORY_SCOPE_AGENT) < tgt) {}
            __builtin_amdgcn_fence(__ATOMIC_ACQUIRE, "agent");
        }
    }
}

// ---------------- phase 3: out[o] = h . Wfc[o,:] + bfc[o] ----------------------
__global__ __launch_bounds__(64)
void fc_kernel(const float* __restrict__ h, const float* __restrict__ Wfc,
               const float* __restrict__ bfc, float* __restrict__ out)
{
    const int o = blockIdx.x;
    const int L = threadIdx.x;
    const float* wr = Wfc + (size_t)o * HDIM;
    float s = 0.0f;
#pragma unroll
    for (int jj = 0; jj < 8; ++jj) {
        float4 wvv = *(const float4*)(wr + 4 * (L + 64 * jj));
        float4 hv  = *(const float4*)(h  + 4 * (L + 64 * jj));
        s += wvv.x * hv.x + wvv.y * hv.y + wvv.z * hv.z + wvv.w * hv.w;
    }
#pragma unroll
    for (int mask = 1; mask <= 32; mask <<= 1) s += __shfl_xor(s, mask, 64);
    if (L == 0) out[o] = s + bfc[o];
}

// ---------------- launcher -----------------------------------------------------
extern "C" void kernel_launch(void* const* d_in, const int* in_sizes, int n_in,
                              void* d_out, int out_size, void* d_ws, size_t ws_size,
                              hipStream_t stream)
{
    (void)in_sizes; (void)n_in; (void)out_size; (void)ws_size;
    const float* x   = (const float*)d_in[0];
    const float* Wih = (const float*)d_in[1];
    const float* Whh = (const float*)d_in[2];
    const float* bih = (const float*)d_in[3];
    const float* bhh = (const float*)d_in[4];
    const float* Wfc = (const float*)d_in[5];
    const float* bfc = (const float*)d_in[6];
    float* out = (float*)d_out;

    // ws layout: xg bf16 [SEQ][G4] (64 MiB) | hbuf fp32 [2][HDIM] | slots u32 [NBLK]
    __hip_bfloat16* xg  = (__hip_bfloat16*)d_ws;
    float* hbuf         = (float*)((char*)d_ws + (size_t)SEQ * G4 * sizeof(__hip_bfloat16));
    unsigned int* slots = (unsigned int*)(hbuf + 2 * HDIM);

    (void)hipMemsetAsync(hbuf, 0, 2 * HDIM * sizeof(float) + NBLK * sizeof(unsigned int), stream);

    dim3 g1(G4 / BN, SEQ / BM);  // (64, 32)
    hipLaunchKernelGGL(xg_gemm, g1, dim3(256), 0, stream, x, Wih, bih, bhh, xg);

    // lstm_rec needs all 256 blocks co-resident. Prefer the cooperative-launch
    // guarantee; if the API refuses (occupancy check / capture-mode / runtime
    // quirk), fall back to a plain launch: grid==256 with >=1 block/CU on an
    // idle 256-CU device is co-resident by construction. Both paths do the
    // same work, so graph capture records whichever succeeds.
    float* hbuf_arg = hbuf;
    void* args[] = { (void*)&Whh, (void*)&xg, (void*)&hbuf_arg, (void*)&slots };
    hipError_t ce = hipLaunchCooperativeKernel((const void*)lstm_rec, dim3(NBLK), dim3(256),
                                               args, 0, stream);
    if (ce != hipSuccess) {
        hipLaunchKernelGGL(lstm_rec, dim3(NBLK), dim3(256), 0, stream, Whh, xg, hbuf, slots);
    }

    hipLaunchKernelGGL(fc_kernel, dim3(2048), dim3(64), 0, stream, hbuf, Wfc, bfc, out);
}

// Round 4
// 28288.202 us; speedup vs baseline: 2.5153x; 2.5153x over previous
//
#include <hip/hip_runtime.h>
#include <hip/hip_bf16.h>

#define SEQ   4096
#define IDIM  2048
#define HDIM  2048
#define G4    8192
#define NBLK  256

// ---------------- numerics (v_exp2 / v_rcp based, ~1e-6 rel err) ----------------
__device__ __forceinline__ float fast_sig(float x) {
    float e = __builtin_amdgcn_exp2f(-1.4426950408889634f * x);   // exp(-x)
    return __builtin_amdgcn_rcpf(1.0f + e);
}
__device__ __forceinline__ float fast_tanh(float x) {
    float e = __builtin_amdgcn_exp2f(2.8853900817779268f * x);    // exp(2x)
    return 1.0f - 2.0f * __builtin_amdgcn_rcpf(e + 1.0f);
}

// ---------------- phase 1: xg[s][g] = x[s,:] . Wih[g,:] + bih[g] + bhh[g] (bf16 store) ---
#define BM 128
#define BN 128
#define BK 16
#define LSTR (BM + 4)   // 132 words: rows stay 16B-aligned (528 = 33*16), write conflicts 2-way (free)

__global__ __launch_bounds__(256, 4)
void xg_gemm(const float* __restrict__ x, const float* __restrict__ Wih,
             const float* __restrict__ bih, const float* __restrict__ bhh,
             __hip_bfloat16* __restrict__ xg)
{
    __shared__ float As[BK][LSTR];   // [k][s]
    __shared__ float Bs[BK][LSTR];   // [k][g]
    const int t  = threadIdx.x;
    const int bG = blockIdx.x;            // 64 tiles over G4
    const int bS = blockIdx.y;            // 32 tiles over SEQ
    const int s0 = bS * BM, g0 = bG * BN;
    const int tx = t & 15, ty = t >> 4;   // 16x16 thread grid, 8x8 microtile
    const int lr = t >> 1, lk = (t & 1) * 8;

    float acc[8][8];
#pragma unroll
    for (int r = 0; r < 8; ++r)
#pragma unroll
        for (int c = 0; c < 8; ++c) acc[r][c] = 0.0f;

    const float* xp = x   + (size_t)(s0 + lr) * IDIM + lk;
    const float* wp = Wih + (size_t)(g0 + lr) * IDIM + lk;

    for (int k0 = 0; k0 < IDIM; k0 += BK) {
        float4 a0 = *(const float4*)(xp + k0);
        float4 a1 = *(const float4*)(xp + k0 + 4);
        float4 b0 = *(const float4*)(wp + k0);
        float4 b1 = *(const float4*)(wp + k0 + 4);
        __syncthreads();
        As[lk+0][lr] = a0.x; As[lk+1][lr] = a0.y; As[lk+2][lr] = a0.z; As[lk+3][lr] = a0.w;
        As[lk+4][lr] = a1.x; As[lk+5][lr] = a1.y; As[lk+6][lr] = a1.z; As[lk+7][lr] = a1.w;
        Bs[lk+0][lr] = b0.x; Bs[lk+1][lr] = b0.y; Bs[lk+2][lr] = b0.z; Bs[lk+3][lr] = b0.w;
        Bs[lk+4][lr] = b1.x; Bs[lk+5][lr] = b1.y; Bs[lk+6][lr] = b1.z; Bs[lk+7][lr] = b1.w;
        __syncthreads();
#pragma unroll
        for (int k = 0; k < BK; ++k) {
            float4 ra0 = *(const float4*)&As[k][ty*8];
            float4 ra1 = *(const float4*)&As[k][ty*8+4];
            float4 rb0 = *(const float4*)&Bs[k][tx*8];
            float4 rb1 = *(const float4*)&Bs[k][tx*8+4];
            float ra[8] = {ra0.x,ra0.y,ra0.z,ra0.w,ra1.x,ra1.y,ra1.z,ra1.w};
            float rb[8] = {rb0.x,rb0.y,rb0.z,rb0.w,rb1.x,rb1.y,rb1.z,rb1.w};
#pragma unroll
            for (int r = 0; r < 8; ++r)
#pragma unroll
                for (int c = 0; c < 8; ++c) acc[r][c] += ra[r] * rb[c];
        }
    }

    float bias[8];
#pragma unroll
    for (int c = 0; c < 8; ++c) {
        int g = g0 + tx*8 + c;
        bias[c] = bih[g] + bhh[g];
    }
#pragma unroll
    for (int r = 0; r < 8; ++r) {
        union { __hip_bfloat16 h[8]; uint4 u; } pk;
#pragma unroll
        for (int c = 0; c < 8; ++c) pk.h[c] = __float2bfloat16(acc[r][c] + bias[c]);
        *(uint4*)&xg[(size_t)(s0 + ty*8 + r) * G4 + g0 + tx*8] = pk.u;
    }
}

// ---------------- phase 2: persistent LSTM recurrence --------------------------
// 256 blocks x 256 threads, 1 block/CU. Block b owns h indices [8b, 8b+8).
// Wave w = gate w (i,f,g,o). Lane L: rg=L>>4 (2 rows: m=2rg,2rg+1), cg=L&15
// (col chunks 4*(cg+16j)). W_hh slice lives in VGPRs/AGPRs per thread.
//
// FENCELESS cross-block sync (the round-3 fix): all cross-block state (h,
// flags) moves via RELAXED agent-scope atomics, which lower to sc0+sc1
// cache-bypass ops hitting the LLC (the coherence point) directly. Ordering:
//  - producer: __syncthreads() drains vmcnt(0) before s_barrier, so the t0
//    flag store (issued after the barrier) reaches the LLC after all 8 h
//    stores. No buffer_wbl2 needed.
//  - consumer: thread t polls slots[t] and consumes exactly h[8t..8t+8],
//    which block t produced — a pure per-thread dependency chain through the
//    LLC. h loads are relaxed-agent 8B atomics (LLC-direct), so no
//    buffer_inv needed. Workgroup-scope acquire = waitcnt only (compiler
//    ordering belt, no cache maintenance).
// This removes the per-step agent release/acquire (buffer_wbl2 sc1 /
// buffer_inv sc1 every step from every wave) that made round 3 sync-bound
// at 16.2 us/step (VALUBusy 2.2%).
__global__ __launch_bounds__(256, 1)
void lstm_rec(const float* __restrict__ Whh,
              const __hip_bfloat16* __restrict__ xg,
              float* __restrict__ hbuf,            // [2][HDIM], zeroed
              unsigned int* __restrict__ slots)    // [NBLK], zeroed
{
    __shared__ float hsh[HDIM];
    __shared__ float gsum[4][8];
    __shared__ float xgl[32];
    __shared__ float csh[8];

    const int t  = threadIdx.x;
    const int b  = blockIdx.x;
    const int w  = t >> 6;
    const int L  = t & 63;
    const int rg = L >> 4;
    const int cg = L & 15;

    float4 wv[2][32];
#pragma unroll
    for (int mp = 0; mp < 2; ++mp) {
        const float* rp = Whh + (size_t)(w * HDIM + 8 * b + 2 * rg + mp) * HDIM + 4 * cg;
#pragma unroll
        for (int j = 0; j < 32; ++j) wv[mp][j] = *(const float4*)(rp + 64 * j);
    }
    if (t < 8) csh[t] = 0.0f;

    for (int s = 0; s < SEQ; ++s) {
        const float* hr = hbuf + (s & 1) * HDIM;
        float*       hw = hbuf + ((s + 1) & 1) * HDIM;

        // stage h_s via LLC-direct 8B atomic loads (fresh by construction:
        // producer block t's flag was observed by this thread at end of the
        // previous iteration; s=0 reads memset zeros)
        const unsigned long long* hr64 = (const unsigned long long*)(hr + 8 * t);
        unsigned long long u0 = __hip_atomic_load(hr64 + 0, __ATOMIC_RELAXED, __HIP_MEMORY_SCOPE_AGENT);
        unsigned long long u1 = __hip_atomic_load(hr64 + 1, __ATOMIC_RELAXED, __HIP_MEMORY_SCOPE_AGENT);
        unsigned long long u2 = __hip_atomic_load(hr64 + 2, __ATOMIC_RELAXED, __HIP_MEMORY_SCOPE_AGENT);
        unsigned long long u3 = __hip_atomic_load(hr64 + 3, __ATOMIC_RELAXED, __HIP_MEMORY_SCOPE_AGENT);
        float xval = 0.0f;
        if (t < 32)
            xval = __bfloat162float(xg[(size_t)s * G4 + (size_t)(t >> 3) * HDIM + 8 * b + (t & 7)]);
        unsigned long long* sh64 = (unsigned long long*)&hsh[8 * t];
        sh64[0] = u0; sh64[1] = u1; sh64[2] = u2; sh64[3] = u3;
        if (t < 32) xgl[t] = xval;
        __syncthreads();                                   // #1

        float a0 = 0.0f, a1 = 0.0f;
#pragma unroll
        for (int j = 0; j < 32; ++j) {
            float4 hv = *(const float4*)&hsh[4 * (cg + 16 * j)];
            a0 += wv[0][j].x * hv.x; a0 += wv[0][j].y * hv.y;
            a0 += wv[0][j].z * hv.z; a0 += wv[0][j].w * hv.w;
            a1 += wv[1][j].x * hv.x; a1 += wv[1][j].y * hv.y;
            a1 += wv[1][j].z * hv.z; a1 += wv[1][j].w * hv.w;
        }
#pragma unroll
        for (int mask = 1; mask <= 8; mask <<= 1) {        // reduce over cg (16 lanes)
            a0 += __shfl_xor(a0, mask, 64);
            a1 += __shfl_xor(a1, mask, 64);
        }
        if (cg == 0) { gsum[w][2 * rg] = a0; gsum[w][2 * rg + 1] = a1; }
        __syncthreads();                                   // #2

        if (t < 8) {
            float pi = gsum[0][t] + xgl[t];
            float pf = gsum[1][t] + xgl[8 + t];
            float pg = gsum[2][t] + xgl[16 + t];
            float po = gsum[3][t] + xgl[24 + t];
            float c  = fast_sig(pf) * csh[t] + fast_sig(pi) * fast_tanh(pg);
            csh[t] = c;
            float h  = fast_sig(po) * fast_tanh(c);
            __hip_atomic_store(&hw[8 * b + t], h, __ATOMIC_RELAXED, __HIP_MEMORY_SCOPE_AGENT);
        }
        __syncthreads();   // #3: drains vmcnt(0) -> h stores are at the LLC

        if (t == 0)
            __hip_atomic_store(&slots[b], (unsigned int)(s + 1),
                               __ATOMIC_RELAXED, __HIP_MEMORY_SCOPE_AGENT);
        if (s + 1 < SEQ) {
            const unsigned int tgt = (unsigned int)(s + 1);
            while (__hip_atomic_load(&slots[t], __ATOMIC_RELAXED,
                                     __HIP_MEMORY_SCOPE_AGENT) < tgt) {}
            __builtin_amdgcn_fence(__ATOMIC_ACQUIRE, "workgroup");  // waitcnt only, no cache inv
        }
    }
}

// ---------------- phase 3: out[o] = h . Wfc[o,:] + bfc[o] ----------------------
__global__ __launch_bounds__(64)
void fc_kernel(const float* __restrict__ h, const float* __restrict__ Wfc,
               const float* __restrict__ bfc, float* __restrict__ out)
{
    const int o = blockIdx.x;
    const int L = threadIdx.x;
    const float* wr = Wfc + (size_t)o * HDIM;
    float s = 0.0f;
#pragma unroll
    for (int jj = 0; jj < 8; ++jj) {
        float4 wvv = *(const float4*)(wr + 4 * (L + 64 * jj));
        float4 hv  = *(const float4*)(h  + 4 * (L + 64 * jj));
        s += wvv.x * hv.x + wvv.y * hv.y + wvv.z * hv.z + wvv.w * hv.w;
    }
#pragma unroll
    for (int mask = 1; mask <= 32; mask <<= 1) s += __shfl_xor(s, mask, 64);
    if (L == 0) out[o] = s + bfc[o];
}

// ---------------- launcher -----------------------------------------------------
extern "C" void kernel_launch(void* const* d_in, const int* in_sizes, int n_in,
                              void* d_out, int out_size, void* d_ws, size_t ws_size,
                              hipStream_t stream)
{
    (void)in_sizes; (void)n_in; (void)out_size; (void)ws_size;
    const float* x   = (const float*)d_in[0];
    const float* Wih = (const float*)d_in[1];
    const float* Whh = (const float*)d_in[2];
    const float* bih = (const float*)d_in[3];
    const float* bhh = (const float*)d_in[4];
    const float* Wfc = (const float*)d_in[5];
    const float* bfc = (const float*)d_in[6];
    float* out = (float*)d_out;

    // ws layout: xg bf16 [SEQ][G4] (64 MiB) | hbuf fp32 [2][HDIM] | slots u32 [NBLK]
    __hip_bfloat16* xg  = (__hip_bfloat16*)d_ws;
    float* hbuf         = (float*)((char*)d_ws + (size_t)SEQ * G4 * sizeof(__hip_bfloat16));
    unsigned int* slots = (unsigned int*)(hbuf + 2 * HDIM);

    (void)hipMemsetAsync(hbuf, 0, 2 * HDIM * sizeof(float) + NBLK * sizeof(unsigned int), stream);

    dim3 g1(G4 / BN, SEQ / BM);  // (64, 32)
    hipLaunchKernelGGL(xg_gemm, g1, dim3(256), 0, stream, x, Wih, bih, bhh, xg);

    // lstm_rec needs all 256 blocks co-resident. Prefer the cooperative-launch
    // guarantee; if the API refuses, fall back to a plain launch: grid==256
    // with 1 block/CU on an idle 256-CU device is co-resident by construction.
    float* hbuf_arg = hbuf;
    void* args[] = { (void*)&Whh, (void*)&xg, (void*)&hbuf_arg, (void*)&slots };
    hipError_t ce = hipLaunchCooperativeKernel((const void*)lstm_rec, dim3(NBLK), dim3(256),
                                               args, 0, stream);
    if (ce != hipSuccess) {
        hipLaunchKernelGGL(lstm_rec, dim3(NBLK), dim3(256), 0, stream, Whh, xg, hbuf, slots);
    }

    hipLaunchKernelGGL(fc_kernel, dim3(2048), dim3(64), 0, stream, hbuf, Wfc, bfc, out);
}

// Round 5
// 24994.890 us; speedup vs baseline: 2.8467x; 1.1318x over previous
//
#include <hip/hip_runtime.h>
#include <hip/hip_bf16.h>
#include <hip/hip_fp16.h>

#define SEQ   4096
#define IDIM  2048
#define HDIM  2048
#define G4    8192
#define NBLK  256

// ---------------- numerics (v_exp2 / v_rcp based, ~1e-6 rel err) ----------------
__device__ __forceinline__ float fast_sig(float x) {
    float e = __builtin_amdgcn_exp2f(-1.4426950408889634f * x);   // exp(-x)
    return __builtin_amdgcn_rcpf(1.0f + e);
}
__device__ __forceinline__ float fast_tanh(float x) {
    float e = __builtin_amdgcn_exp2f(2.8853900817779268f * x);    // exp(2x)
    return 1.0f - 2.0f * __builtin_amdgcn_rcpf(e + 1.0f);
}
__device__ __forceinline__ unsigned short f2h(float f) {
    __half h = __float2half_rn(f);
    union { __half h; unsigned short s; } c; c.h = h; return c.s;
}
__device__ __forceinline__ float h2f(unsigned short u) {
    union { unsigned short s; __half h; } c; c.s = u; return __half2float(c.h);
}

// ---------------- phase 1: xg[s][g] = x[s,:] . Wih[g,:] + bih[g] + bhh[g] (bf16 store) ---
#define BM 128
#define BN 128
#define BK 16
#define LSTR (BM + 4)   // 132 words: rows stay 16B-aligned (528 = 33*16), write conflicts 2-way (free)

__global__ __launch_bounds__(256, 4)
void xg_gemm(const float* __restrict__ x, const float* __restrict__ Wih,
             const float* __restrict__ bih, const float* __restrict__ bhh,
             __hip_bfloat16* __restrict__ xg)
{
    __shared__ float As[BK][LSTR];   // [k][s]
    __shared__ float Bs[BK][LSTR];   // [k][g]
    const int t  = threadIdx.x;
    const int bG = blockIdx.x;            // 64 tiles over G4
    const int bS = blockIdx.y;            // 32 tiles over SEQ
    const int s0 = bS * BM, g0 = bG * BN;
    const int tx = t & 15, ty = t >> 4;   // 16x16 thread grid, 8x8 microtile
    const int lr = t >> 1, lk = (t & 1) * 8;

    float acc[8][8];
#pragma unroll
    for (int r = 0; r < 8; ++r)
#pragma unroll
        for (int c = 0; c < 8; ++c) acc[r][c] = 0.0f;

    const float* xp = x   + (size_t)(s0 + lr) * IDIM + lk;
    const float* wp = Wih + (size_t)(g0 + lr) * IDIM + lk;

    for (int k0 = 0; k0 < IDIM; k0 += BK) {
        float4 a0 = *(const float4*)(xp + k0);
        float4 a1 = *(const float4*)(xp + k0 + 4);
        float4 b0 = *(const float4*)(wp + k0);
        float4 b1 = *(const float4*)(wp + k0 + 4);
        __syncthreads();
        As[lk+0][lr] = a0.x; As[lk+1][lr] = a0.y; As[lk+2][lr] = a0.z; As[lk+3][lr] = a0.w;
        As[lk+4][lr] = a1.x; As[lk+5][lr] = a1.y; As[lk+6][lr] = a1.z; As[lk+7][lr] = a1.w;
        Bs[lk+0][lr] = b0.x; Bs[lk+1][lr] = b0.y; Bs[lk+2][lr] = b0.z; Bs[lk+3][lr] = b0.w;
        Bs[lk+4][lr] = b1.x; Bs[lk+5][lr] = b1.y; Bs[lk+6][lr] = b1.z; Bs[lk+7][lr] = b1.w;
        __syncthreads();
#pragma unroll
        for (int k = 0; k < BK; ++k) {
            float4 ra0 = *(const float4*)&As[k][ty*8];
            float4 ra1 = *(const float4*)&As[k][ty*8+4];
            float4 rb0 = *(const float4*)&Bs[k][tx*8];
            float4 rb1 = *(const float4*)&Bs[k][tx*8+4];
            float ra[8] = {ra0.x,ra0.y,ra0.z,ra0.w,ra1.x,ra1.y,ra1.z,ra1.w};
            float rb[8] = {rb0.x,rb0.y,rb0.z,rb0.w,rb1.x,rb1.y,rb1.z,rb1.w};
#pragma unroll
            for (int r = 0; r < 8; ++r)
#pragma unroll
                for (int c = 0; c < 8; ++c) acc[r][c] += ra[r] * rb[c];
        }
    }

    float bias[8];
#pragma unroll
    for (int c = 0; c < 8; ++c) {
        int g = g0 + tx*8 + c;
        bias[c] = bih[g] + bhh[g];
    }
#pragma unroll
    for (int r = 0; r < 8; ++r) {
        union { __hip_bfloat16 h[8]; uint4 u; } pk;
#pragma unroll
        for (int c = 0; c < 8; ++c) pk.h[c] = __float2bfloat16(acc[r][c] + bias[c]);
        *(uint4*)&xg[(size_t)(s0 + ty*8 + r) * G4 + g0 + tx*8] = pk.u;
    }
}

// ---------------- phase 2: persistent LSTM recurrence --------------------------
// 256 blocks x 256 threads, 1 block/CU. Block b owns h indices [8b, 8b+8).
// Wave w = gate w (i,f,g,o). Lane L: rg=L>>4 (2 rows), cg=L&15 (col chunks).
//
// Round-5 sync: SELF-VALIDATING 8B ATOMIC UNITS. Block b publishes its 8 h
// values as 3 units msg[parity][j][b], each unit = {tag:16, 3x fp16 h}. An 8B
// relaxed agent atomic (sc0+sc1, LLC-direct) is indivisible, so a fresh tag
// implies fresh data in the same unit: detection and data arrive in ONE LLC
// round trip, no fences, no separate flag line, no producer drain (tag rides
// inside each atomic store). Units are interleaved [j][block] so consecutive
// lanes poll consecutive 8B (coalesced) and polling spreads over 96 lines
// (round 4's flood was 65536 pollers on 16 lines). Parity double-buffer makes
// overwrite-before-consume impossible (block b republishes a parity slot only
// after every block consumed the previous value - barrier transitivity).
__global__ __launch_bounds__(256, 1)
void lstm_rec(const float* __restrict__ Whh,
              const __hip_bfloat16* __restrict__ xg,
              float* __restrict__ hout,                 // [HDIM] final h (fp32)
              unsigned long long* __restrict__ msg)     // [2][3][NBLK], tags zeroed
{
    __shared__ float hsh[HDIM];
    __shared__ float gsum[4][8];
    __shared__ float xgl[32];
    __shared__ float hloc[8];

    const int t  = threadIdx.x;
    const int b  = blockIdx.x;
    const int w  = t >> 6;
    const int L  = t & 63;
    const int rg = L >> 4;
    const int cg = L & 15;

    float4 wv[2][32];
#pragma unroll
    for (int mp = 0; mp < 2; ++mp) {
        const float* rp = Whh + (size_t)(w * HDIM + 8 * b + 2 * rg + mp) * HDIM + 4 * cg;
#pragma unroll
        for (int j = 0; j < 32; ++j) wv[mp][j] = *(const float4*)(rp + 64 * j);
    }

    float creg = 0.0f;              // cell state (meaningful for t<8 only)
    float hreg[8];
#pragma unroll
    for (int k = 0; k < 8; ++k) hreg[k] = 0.0f;   // h_0 = 0
    float xval = 0.0f;
    if (t < 32)
        xval = __bfloat162float(xg[(size_t)(t >> 3) * HDIM + 8 * b + (t & 7)]);  // s=0

    for (int s = 0; s < SEQ; ++s) {
        // stage h_s (from polled registers) + xg_s (prefetched)
        float4 hv0 = { hreg[0], hreg[1], hreg[2], hreg[3] };
        float4 hv1 = { hreg[4], hreg[5], hreg[6], hreg[7] };
        *(float4*)&hsh[8 * t]     = hv0;
        *(float4*)&hsh[8 * t + 4] = hv1;
        if (t < 32) xgl[t] = xval;
        __syncthreads();                                   // #1

        float a0 = 0.0f, a1 = 0.0f;
#pragma unroll
        for (int j = 0; j < 32; ++j) {
            float4 hv = *(const float4*)&hsh[4 * (cg + 16 * j)];
            a0 += wv[0][j].x * hv.x; a0 += wv[0][j].y * hv.y;
            a0 += wv[0][j].z * hv.z; a0 += wv[0][j].w * hv.w;
            a1 += wv[1][j].x * hv.x; a1 += wv[1][j].y * hv.y;
            a1 += wv[1][j].z * hv.z; a1 += wv[1][j].w * hv.w;
        }
#pragma unroll
        for (int mask = 1; mask <= 8; mask <<= 1) {        // reduce over cg (16 lanes)
            a0 += __shfl_xor(a0, mask, 64);
            a1 += __shfl_xor(a1, mask, 64);
        }
        if (cg == 0) { gsum[w][2 * rg] = a0; gsum[w][2 * rg + 1] = a1; }
        __syncthreads();                                   // #2

        // gates: wave 0 only; hloc handoff to the packers (t<3) is same-wave,
        // in-order LDS -> no barrier #3 needed.
        if (t < 8) {
            float pi = gsum[0][t] + xgl[t];
            float pf = gsum[1][t] + xgl[8 + t];
            float pg = gsum[2][t] + xgl[16 + t];
            float po = gsum[3][t] + xgl[24 + t];
            float c  = fast_sig(pf) * creg + fast_sig(pi) * fast_tanh(pg);
            creg = c;
            float h  = fast_sig(po) * fast_tanh(c);
            hloc[t] = h;
            if (s == SEQ - 1) hout[8 * b + t] = h;
        }

        if (s + 1 < SEQ) {
            const int p = (s + 1) & 1;
            // publish 3 self-validating units (wave 0)
            if (t < 3) {
                float v0 = hloc[3 * t], v1 = hloc[3 * t + 1];
                float v2 = (3 * t + 2 < 8) ? hloc[3 * t + 2] : 0.0f;
                unsigned long long u = (unsigned long long)(unsigned short)(s + 1)
                    | ((unsigned long long)f2h(v0) << 16)
                    | ((unsigned long long)f2h(v1) << 32)
                    | ((unsigned long long)f2h(v2) << 48);
                __hip_atomic_store(&msg[(size_t)(p * 3 + t) * NBLK + b], u,
                                   __ATOMIC_RELAXED, __HIP_MEMORY_SCOPE_AGENT);
            }
            // prefetch xg for s+1 (latency hidden under the poll)
            if (t < 32)
                xval = __bfloat162float(xg[(size_t)(s + 1) * G4 + (size_t)(t >> 3) * HDIM + 8 * b + (t & 7)]);
            // poll block t's 3 units; data rides with the tag
            const unsigned long long* p0 = &msg[(size_t)(p * 3 + 0) * NBLK + t];
            const unsigned long long* p1 = &msg[(size_t)(p * 3 + 1) * NBLK + t];
            const unsigned long long* p2 = &msg[(size_t)(p * 3 + 2) * NBLK + t];
            const unsigned tgt = (unsigned)(s + 1);
            unsigned long long v0, v1, v2;
            do {
                v0 = __hip_atomic_load(p0, __ATOMIC_RELAXED, __HIP_MEMORY_SCOPE_AGENT);
                v1 = __hip_atomic_load(p1, __ATOMIC_RELAXED, __HIP_MEMORY_SCOPE_AGENT);
                v2 = __hip_atomic_load(p2, __ATOMIC_RELAXED, __HIP_MEMORY_SCOPE_AGENT);
            } while ((unsigned)(v0 & 0xFFFFu) < tgt ||
                     (unsigned)(v1 & 0xFFFFu) < tgt ||
                     (unsigned)(v2 & 0xFFFFu) < tgt);
            hreg[0] = h2f((unsigned short)(v0 >> 16));
            hreg[1] = h2f((unsigned short)(v0 >> 32));
            hreg[2] = h2f((unsigned short)(v0 >> 48));
            hreg[3] = h2f((unsigned short)(v1 >> 16));
            hreg[4] = h2f((unsigned short)(v1 >> 32));
            hreg[5] = h2f((unsigned short)(v1 >> 48));
            hreg[6] = h2f((unsigned short)(v2 >> 16));
            hreg[7] = h2f((unsigned short)(v2 >> 32));
        }
    }
}

// ---------------- phase 3: out[o] = h . Wfc[o,:] + bfc[o] ----------------------
__global__ __launch_bounds__(64)
void fc_kernel(const float* __restrict__ h, const float* __restrict__ Wfc,
               const float* __restrict__ bfc, float* __restrict__ out)
{
    const int o = blockIdx.x;
    const int L = threadIdx.x;
    const float* wr = Wfc + (size_t)o * HDIM;
    float s = 0.0f;
#pragma unroll
    for (int jj = 0; jj < 8; ++jj) {
        float4 wvv = *(const float4*)(wr + 4 * (L + 64 * jj));
        float4 hv  = *(const float4*)(h  + 4 * (L + 64 * jj));
        s += wvv.x * hv.x + wvv.y * hv.y + wvv.z * hv.z + wvv.w * hv.w;
    }
#pragma unroll
    for (int mask = 1; mask <= 32; mask <<= 1) s += __shfl_xor(s, mask, 64);
    if (L == 0) out[o] = s + bfc[o];
}

// ---------------- launcher -----------------------------------------------------
extern "C" void kernel_launch(void* const* d_in, const int* in_sizes, int n_in,
                              void* d_out, int out_size, void* d_ws, size_t ws_size,
                              hipStream_t stream)
{
    (void)in_sizes; (void)n_in; (void)out_size; (void)ws_size;
    const float* x   = (const float*)d_in[0];
    const float* Wih = (const float*)d_in[1];
    const float* Whh = (const float*)d_in[2];
    const float* bih = (const float*)d_in[3];
    const float* bhh = (const float*)d_in[4];
    const float* Wfc = (const float*)d_in[5];
    const float* bfc = (const float*)d_in[6];
    float* out = (float*)d_out;

    // ws layout: xg bf16 [SEQ][G4] (64 MiB) | hout fp32 [HDIM] | msg u64 [2][3][NBLK]
    __hip_bfloat16* xg       = (__hip_bfloat16*)d_ws;
    float* hout              = (float*)((char*)d_ws + (size_t)SEQ * G4 * sizeof(__hip_bfloat16));
    unsigned long long* msg  = (unsigned long long*)(hout + HDIM);

    // ws is poisoned 0xAA before every launch -> tags would read as fresh; MUST zero.
    (void)hipMemsetAsync(msg, 0, 2 * 3 * NBLK * sizeof(unsigned long long), stream);

    dim3 g1(G4 / BN, SEQ / BM);  // (64, 32)
    hipLaunchKernelGGL(xg_gemm, g1, dim3(256), 0, stream, x, Wih, bih, bhh, xg);

    // lstm_rec needs all 256 blocks co-resident. Prefer the cooperative-launch
    // guarantee; if the API refuses, fall back to a plain launch: grid==256
    // with 1 block/CU on an idle 256-CU device is co-resident by construction.
    float* hout_arg = hout;
    unsigned long long* msg_arg = msg;
    void* args[] = { (void*)&Whh, (void*)&xg, (void*)&hout_arg, (void*)&msg_arg };
    hipError_t ce = hipLaunchCooperativeKernel((const void*)lstm_rec, dim3(NBLK), dim3(256),
                                               args, 0, stream);
    if (ce != hipSuccess) {
        hipLaunchKernelGGL(lstm_rec, dim3(NBLK), dim3(256), 0, stream, Whh, xg, hout, msg);
    }

    hipLaunchKernelGGL(fc_kernel, dim3(2048), dim3(64), 0, stream, hout, Wfc, bfc, out);
}